// Round 11
// baseline (134.054 us; speedup 1.0000x reference)
//
#include <hip/hip_runtime.h>

#define COLS 2048
#define KSEL 256
#define TPB  256

// LDS layout (word offsets); two rows (A,B) per block
#define HA    0        // 1024-bin hist row A
#define HB    1024     // 1024-bin hist row B
#define WOFFA 2048     // 4 wave totals A
#define WOFFB 2052
#define BCA   2056     // scan broadcast {T,kk,na} A
#define BCB   2060
#define BC2A  2064     // radix broadcast {T,kk,ne} A
#define BC2B  2068
#define CA    2072     // compact counter A
#define CB    2073
#define BUFA  2080     // compact list A, cap 64
#define BUFB  2144
#define NWORDS 2208

// One block per TWO rows; thread t owns cols 8t..8t+7 of each row (thread
// order = column order). Exact top-K radix select per row: one 1024-bin pass
// on score bits[30:21], then per-row ballot-radix tails run in PARALLEL on
// wave0 (row A) and wave1 (row B). Exact refine fallbacks for fat bins.
// score = as_uint(x*imp) & 0x7FFFFFFF == bits of |x|*|imp| (uint-monotone).
// Tie handling matches jax.lax.top_k (lower column index first).
__global__ __launch_bounds__(TPB)
void CompetitiveSelection_topk_kernel(const float* __restrict__ x,
                                      const float* __restrict__ imp,
                                      float* __restrict__ out)
{
    __shared__ __align__(16) unsigned lds[NWORDS];
    const int tid  = threadIdx.x;
    const int lane = tid & 63;
    const int wid  = tid >> 6;
    const long baseA = (long)(2 * blockIdx.x) * COLS + tid * 8;
    const long baseB = baseA + COLS;

    // ---- clear hists + counters ----
    const uint4 z4 = make_uint4(0, 0, 0, 0);
    *(uint4*)&lds[HA + 4 * tid] = z4;
    *(uint4*)&lds[HB + 4 * tid] = z4;
    if (tid < 2) lds[CA + tid] = 0;
    __syncthreads();

    // ---- load + score-once + first-pass atomics (bits[30:21]) ----
    float4 a0 = *(const float4*)(x + baseA);
    float4 a1 = *(const float4*)(x + baseA + 4);
    float4 b0 = *(const float4*)(x + baseB);
    float4 b1 = *(const float4*)(x + baseB + 4);
    float4 i0 = *(const float4*)(imp + tid * 8);
    float4 i1 = *(const float4*)(imp + tid * 8 + 4);
    float xsA[8] = {a0.x, a0.y, a0.z, a0.w, a1.x, a1.y, a1.z, a1.w};
    float xsB[8] = {b0.x, b0.y, b0.z, b0.w, b1.x, b1.y, b1.z, b1.w};
    float ivv[8] = {i0.x, i0.y, i0.z, i0.w, i1.x, i1.y, i1.z, i1.w};
    unsigned scA[8], scB[8];
#pragma unroll
    for (int j = 0; j < 8; ++j) {
        scA[j] = __float_as_uint(xsA[j] * ivv[j]) & 0x7FFFFFFFu;
        scB[j] = __float_as_uint(xsB[j] * ivv[j]) & 0x7FFFFFFFu;
        atomicAdd(&lds[HA + (scA[j] >> 21)], 1u);
        atomicAdd(&lds[HB + (scB[j] >> 21)], 1u);
    }
    __syncthreads();

    unsigned TA = 0, kkA = KSEL, naA = 0, hmA = 0x80000000u;
    unsigned TB = 0, kkB = KSEL, naB = 0, hmB = 0x80000000u;
    int nbA = 31, nbB = 31;

    // ---- shared scan phase for both rows (actX, sX block-uniform) ----
    auto scanBoth = [&](bool actA, int sA, bool actB, int sB) {
        uint4 hA4, hB4; unsigned SA = 0, SB = 0, totA = 0, totB = 0;
        if (actA) {
            hA4 = *(const uint4*)&lds[HA + 4 * tid];
            totA = hA4.x + hA4.y + hA4.z + hA4.w; SA = totA;
#pragma unroll
            for (int off = 1; off < 64; off <<= 1) {
                unsigned u = __shfl_down(SA, off);
                if (lane + off < 64) SA += u;
            }
            if (lane == 0) lds[WOFFA + wid] = SA;
        }
        if (actB) {
            hB4 = *(const uint4*)&lds[HB + 4 * tid];
            totB = hB4.x + hB4.y + hB4.z + hB4.w; SB = totB;
#pragma unroll
            for (int off = 1; off < 64; off <<= 1) {
                unsigned u = __shfl_down(SB, off);
                if (lane + off < 64) SB += u;
            }
            if (lane == 0) lds[WOFFB + wid] = SB;
        }
        __syncthreads();
        if (actA) {
            unsigned above = SA - totA;
#pragma unroll
            for (int w = 0; w < 4; ++w) above += (w > wid) ? lds[WOFFA + w] : 0u;
            unsigned cnt[4] = {hA4.x, hA4.y, hA4.z, hA4.w};
            int cc = -1; unsigned cab = 0, cnb = 0;
#pragma unroll
            for (int b = 3; b >= 0; --b) {
                if (cc < 0 && above < kkA && above + cnt[b] >= kkA) {
                    cc = 4 * tid + b; cab = above; cnb = cnt[b];
                }
                above += cnt[b];
            }
            if (cc >= 0) {
                lds[BCA + 0] = TA | ((unsigned)cc << sA);
                lds[BCA + 1] = kkA - cab;
                lds[BCA + 2] = cnb;
            }
        }
        if (actB) {
            unsigned above = SB - totB;
#pragma unroll
            for (int w = 0; w < 4; ++w) above += (w > wid) ? lds[WOFFB + w] : 0u;
            unsigned cnt[4] = {hB4.x, hB4.y, hB4.z, hB4.w};
            int cc = -1; unsigned cab = 0, cnb = 0;
#pragma unroll
            for (int b = 3; b >= 0; --b) {
                if (cc < 0 && above < kkB && above + cnt[b] >= kkB) {
                    cc = 4 * tid + b; cab = above; cnb = cnt[b];
                }
                above += cnt[b];
            }
            if (cc >= 0) {
                lds[BCB + 0] = TB | ((unsigned)cc << sB);
                lds[BCB + 1] = kkB - cab;
                lds[BCB + 2] = cnb;
            }
        }
        __syncthreads();
        if (actA) { TA = lds[BCA]; kkA = lds[BCA + 1]; naA = lds[BCA + 2];
                    hmA |= (0x3FFu << sA); nbA = sA; }
        if (actB) { TB = lds[BCB]; kkB = lds[BCB + 1]; naB = lds[BCB + 2];
                    hmB |= (0x3FFu << sB); nbB = sB; }
    };

    scanBoth(true, 21, true, 21);

    // ---- rare: refine from registers while a boundary bin stays fat ----
    while ((naA > 64u && nbA > 0) || (naB > 64u && nbB > 0)) {
        bool rA = naA > 64u && nbA > 0, rB = naB > 64u && nbB > 0;
        int sA2 = (nbA > 10) ? nbA - 10 : 0, sB2 = (nbB > 10) ? nbB - 10 : 0;
        if (rA) *(uint4*)&lds[HA + 4 * tid] = z4;
        if (rB) *(uint4*)&lds[HB + 4 * tid] = z4;
        __syncthreads();
        if (rA) {
#pragma unroll
            for (int j = 0; j < 8; ++j)
                if ((scA[j] & hmA) == TA)
                    atomicAdd(&lds[HA + ((scA[j] >> sA2) & 1023u)], 1u);
        }
        if (rB) {
#pragma unroll
            for (int j = 0; j < 8; ++j)
                if ((scB[j] & hmB) == TB)
                    atomicAdd(&lds[HB + ((scB[j] >> sB2) & 1023u)], 1u);
        }
        __syncthreads();
        scanBoth(rA, sA2, rB, sB2);
    }

    // ---- compact survivors (<=64 per active row) ----
    if (nbA > 0) {
        unsigned c = 0;
#pragma unroll
        for (int j = 0; j < 8; ++j) c += ((scA[j] & hmA) == TA) ? 1u : 0u;
        unsigned S = c;
#pragma unroll
        for (int off = 1; off < 64; off <<= 1) {
            unsigned u = __shfl_up(S, off);
            if (lane >= off) S += u;
        }
        unsigned rb = 0;
        if (lane == 63) rb = atomicAdd(&lds[CA], S);
        unsigned p = BUFA + __shfl(rb, 63) + S - c;
#pragma unroll
        for (int j = 0; j < 8; ++j)
            if ((scA[j] & hmA) == TA) lds[p++] = scA[j];
    }
    if (nbB > 0) {
        unsigned c = 0;
#pragma unroll
        for (int j = 0; j < 8; ++j) c += ((scB[j] & hmB) == TB) ? 1u : 0u;
        unsigned S = c;
#pragma unroll
        for (int off = 1; off < 64; off <<= 1) {
            unsigned u = __shfl_up(S, off);
            if (lane >= off) S += u;
        }
        unsigned rb = 0;
        if (lane == 63) rb = atomicAdd(&lds[CB], S);
        unsigned p = BUFB + __shfl(rb, 63) + S - c;
#pragma unroll
        for (int j = 0; j < 8; ++j)
            if ((scB[j] & hmB) == TB) lds[p++] = scB[j];
    }
    __syncthreads();

    // ---- parallel ballot-radix tails: wave0 -> row A, wave1 -> row B ----
    if (wid == 0 && nbA > 0) {
        unsigned v = ((unsigned)lane < naA) ? lds[BUFA + lane] : 0u;
        unsigned long long M = __ballot((unsigned)lane < naA);
        unsigned tl = 0, k2 = kkA;
        for (int b = nbA - 1; b >= 0; --b) {
            unsigned long long ones = __ballot((v >> b) & 1u) & M;
            unsigned c1 = (unsigned)__popcll(ones);
            if (c1 >= k2) { M = ones; tl |= (1u << b); }
            else          { M &= ~ones; k2 -= c1; }
        }
        if (lane == 0) {
            lds[BC2A + 0] = TA | tl;
            lds[BC2A + 1] = k2;
            lds[BC2A + 2] = (unsigned)__popcll(M);
        }
    }
    if (wid == 1 && nbB > 0) {
        unsigned v = ((unsigned)lane < naB) ? lds[BUFB + lane] : 0u;
        unsigned long long M = __ballot((unsigned)lane < naB);
        unsigned tl = 0, k2 = kkB;
        for (int b = nbB - 1; b >= 0; --b) {
            unsigned long long ones = __ballot((v >> b) & 1u) & M;
            unsigned c1 = (unsigned)__popcll(ones);
            if (c1 >= k2) { M = ones; tl |= (1u << b); }
            else          { M &= ~ones; k2 -= c1; }
        }
        if (lane == 0) {
            lds[BC2B + 0] = TB | tl;
            lds[BC2B + 1] = k2;
            lds[BC2B + 2] = (unsigned)__popcll(M);
        }
    }
    __syncthreads();
    unsigned neA, neB;
    if (nbA > 0) { TA = lds[BC2A]; kkA = lds[BC2A + 1]; neA = lds[BC2A + 2]; }
    else         { neA = naA; }
    if (nbB > 0) { TB = lds[BC2B]; kkB = lds[BC2B + 1]; neB = lds[BC2B + 2]; }
    else         { neB = naB; }

    // ---- epilogue ----
    float* oA = out + baseA;
    float* oB = out + baseB;
    if (neA == kkA && neB == kkB) {        // no boundary-tie split (common)
        float4 p0, p1, q0, q1;
        p0.x = (scA[0] >= TA) ? xsA[0] : 0.0f;
        p0.y = (scA[1] >= TA) ? xsA[1] : 0.0f;
        p0.z = (scA[2] >= TA) ? xsA[2] : 0.0f;
        p0.w = (scA[3] >= TA) ? xsA[3] : 0.0f;
        p1.x = (scA[4] >= TA) ? xsA[4] : 0.0f;
        p1.y = (scA[5] >= TA) ? xsA[5] : 0.0f;
        p1.z = (scA[6] >= TA) ? xsA[6] : 0.0f;
        p1.w = (scA[7] >= TA) ? xsA[7] : 0.0f;
        q0.x = (scB[0] >= TB) ? xsB[0] : 0.0f;
        q0.y = (scB[1] >= TB) ? xsB[1] : 0.0f;
        q0.z = (scB[2] >= TB) ? xsB[2] : 0.0f;
        q0.w = (scB[3] >= TB) ? xsB[3] : 0.0f;
        q1.x = (scB[4] >= TB) ? xsB[4] : 0.0f;
        q1.y = (scB[5] >= TB) ? xsB[5] : 0.0f;
        q1.z = (scB[6] >= TB) ? xsB[6] : 0.0f;
        q1.w = (scB[7] >= TB) ? xsB[7] : 0.0f;
        *(float4*)(oA)     = p0;
        *(float4*)(oA + 4) = p1;
        *(float4*)(oB)     = q0;
        *(float4*)(oB + 4) = q1;
    } else {
        // tie split by lowest column (thread order = column order)
        unsigned eqA = 0, eqB = 0;
#pragma unroll
        for (int j = 0; j < 8; ++j) {
            eqA += (scA[j] == TA) ? 1u : 0u;
            eqB += (scB[j] == TB) ? 1u : 0u;
        }
        unsigned SA = eqA, SB = eqB;
#pragma unroll
        for (int off = 1; off < 64; off <<= 1) {
            unsigned uA = __shfl_up(SA, off);
            unsigned uB = __shfl_up(SB, off);
            if (lane >= off) { SA += uA; SB += uB; }
        }
        if (lane == 63) { lds[WOFFA + wid] = SA; lds[WOFFB + wid] = SB; }
        __syncthreads();
        unsigned addA = 0, addB = 0;
#pragma unroll
        for (int w = 0; w < 4; ++w) {
            addA += (w < wid) ? lds[WOFFA + w] : 0u;
            addB += (w < wid) ? lds[WOFFB + w] : 0u;
        }
        unsigned ebA = addA + SA - eqA;
        unsigned ebB = addB + SB - eqB;
        float o[8], p[8];
#pragma unroll
        for (int j = 0; j < 8; ++j) {
            bool pickA = scA[j] > TA;
            if (scA[j] == TA) { pickA = (ebA < kkA); ebA += 1; }
            o[j] = pickA ? xsA[j] : 0.0f;
            bool pickB = scB[j] > TB;
            if (scB[j] == TB) { pickB = (ebB < kkB); ebB += 1; }
            p[j] = pickB ? xsB[j] : 0.0f;
        }
        *(float4*)(oA)     = make_float4(o[0], o[1], o[2], o[3]);
        *(float4*)(oA + 4) = make_float4(o[4], o[5], o[6], o[7]);
        *(float4*)(oB)     = make_float4(p[0], p[1], p[2], p[3]);
        *(float4*)(oB + 4) = make_float4(p[4], p[5], p[6], p[7]);
    }
}

extern "C" void kernel_launch(void* const* d_in, const int* in_sizes, int n_in,
                              void* d_out, int out_size, void* d_ws, size_t ws_size,
                              hipStream_t stream)
{
    const float* x   = (const float*)d_in[0];
    const float* imp = (const float*)d_in[1];
    float* out       = (float*)d_out;

    const int rows = in_sizes[0] / COLS;   // 32768
    CompetitiveSelection_topk_kernel<<<dim3(rows / 2), dim3(TPB), 0, stream>>>(x, imp, out);
}